// Round 1
// baseline (7064.159 us; speedup 1.0000x reference)
//
#include <hip/hip_runtime.h>

// EncodeProcessDecode (GNS): N=10000 nodes, E=100000 edges, S=10 steps, L=H=128.
// fp32 baseline: register-tiled vector-FMA GEMMs, fused MLP+LN per kernel.

#define NN 10000
#define NE 100000
#define STEPS 10
#define NODE_F 30
#define EDGE_F 4
#define L 128
#define AP 132   // A_s row stride (floats), 128+4 pad (16B-aligned, bank-friendly)
#define BP 36    // B_s row stride (transposed [col][k]), 32+4 pad

// ---------------- device helpers ----------------

// Stage W[k0..k0+32][0..128) transposed into Bs[c*BP + kk]; zero rows past K.
__device__ __forceinline__ void load_B(float* __restrict__ Bs, const float* __restrict__ W,
                                       int K, int k0, int tid) {
#pragma unroll
  for (int p = 0; p < 16; ++p) {
    int idx = tid + p * 256;
    int kk = idx >> 7;        // 0..31
    int c = idx & 127;        // 0..127
    float v = 0.f;
    if (k0 + kk < K) v = W[(size_t)(k0 + kk) * L + c];
    Bs[c * BP + kk] = v;
  }
}

// acc[4][8] += A_s[rows][koff..koff+32) * B_s (transposed chunk)
__device__ __forceinline__ void fma32(const float* __restrict__ As, const float* __restrict__ Bs,
                                      float acc[4][8], int ty, int tx, int koff) {
#pragma unroll
  for (int kk = 0; kk < 32; kk += 4) {
    float4 a[4];
    float4 b[8];
#pragma unroll
    for (int i = 0; i < 4; ++i)
      a[i] = *(const float4*)&As[(ty + 16 * i) * AP + koff + kk];
#pragma unroll
    for (int j = 0; j < 8; ++j)
      b[j] = *(const float4*)&Bs[(tx + 16 * j) * BP + kk];
#pragma unroll
    for (int i = 0; i < 4; ++i)
#pragma unroll
      for (int j = 0; j < 8; ++j) {
        acc[i][j] = fmaf(a[i].x, b[j].x, acc[i][j]);
        acc[i][j] = fmaf(a[i].y, b[j].y, acc[i][j]);
        acc[i][j] = fmaf(a[i].z, b[j].z, acc[i][j]);
        acc[i][j] = fmaf(a[i].w, b[j].w, acc[i][j]);
      }
  }
}

__device__ __forceinline__ void init_bias(float acc[4][8], const float* __restrict__ b, int tx) {
#pragma unroll
  for (int j = 0; j < 8; ++j) {
    float bv = b[tx + 16 * j];
#pragma unroll
    for (int i = 0; i < 4; ++i) acc[i][j] = bv;
  }
}

__device__ __forceinline__ void store_relu(float* __restrict__ As, float acc[4][8], int ty, int tx) {
#pragma unroll
  for (int i = 0; i < 4; ++i)
#pragma unroll
    for (int j = 0; j < 8; ++j)
      As[(ty + 16 * i) * AP + tx + 16 * j] = fmaxf(acc[i][j], 0.f);
}

// One linear layer whose input (K<=128 cols) is already in As.
__device__ __forceinline__ void layer_As(const float* __restrict__ As, float* __restrict__ Bs,
                                         const float* __restrict__ W, const float* __restrict__ bias,
                                         int K, float acc[4][8], int tid, int ty, int tx) {
  init_bias(acc, bias, tx);
  int nc = (K + 31) >> 5;
  for (int bc = 0; bc < nc; ++bc) {
    __syncthreads();                    // guards Bs overwrite + prior As writes
    load_B(Bs, W, K, bc * 32, tid);
    __syncthreads();
    fma32(As, Bs, acc, ty, tx, bc * 32);
  }
}

// Gather 64 rows x 128 floats (row indices from LDS table) into As.
__device__ __forceinline__ void fillA_gather(float* __restrict__ As, const float* __restrict__ base,
                                             const int* __restrict__ ridx, int tid) {
#pragma unroll
  for (int p = 0; p < 8; ++p) {
    int idx = tid + p * 256;
    int r = idx >> 5;         // 0..63
    int c4 = idx & 31;        // float4 col
    float4 v = *(const float4*)&base[(size_t)ridx[r] * L + c4 * 4];
    *(float4*)&As[r * AP + c4 * 4] = v;
  }
}

// In-register LayerNorm over 128 cols; row r lives on 16 consecutive lanes (same ty).
__device__ __forceinline__ void lnorm(float acc[4][8], const float* __restrict__ g,
                                      const float* __restrict__ bt, int tx) {
  float gv[8], bv[8];
#pragma unroll
  for (int j = 0; j < 8; ++j) { gv[j] = g[tx + 16 * j]; bv[j] = bt[tx + 16 * j]; }
#pragma unroll
  for (int i = 0; i < 4; ++i) {
    float s = 0.f, s2 = 0.f;
#pragma unroll
    for (int j = 0; j < 8; ++j) { s += acc[i][j]; s2 += acc[i][j] * acc[i][j]; }
#pragma unroll
    for (int off = 1; off < 16; off <<= 1) {
      s  += __shfl_xor(s, off, 64);
      s2 += __shfl_xor(s2, off, 64);
    }
    float m = s * (1.f / 128.f);
    float var = s2 * (1.f / 128.f) - m * m;   // biased
    float inv = rsqrtf(var + 1e-5f);
#pragma unroll
    for (int j = 0; j < 8; ++j) acc[i][j] = (acc[i][j] - m) * inv * gv[j] + bv[j];
  }
}

// ---------------- kernels ----------------

__global__ __launch_bounds__(256) void enc_node_kernel(
    const float* __restrict__ x,
    const float* __restrict__ W0, const float* __restrict__ b0,
    const float* __restrict__ W1, const float* __restrict__ b1,
    const float* __restrict__ W2, const float* __restrict__ b2,
    const float* __restrict__ g, const float* __restrict__ bt,
    float* __restrict__ hx) {
  __shared__ float As[64 * AP];
  __shared__ float Bs[128 * BP];
  int tid = threadIdx.x, ty = tid >> 4, tx = tid & 15;
  int n0 = blockIdx.x * 64;
  // fill A: 64 x 32, cols >= NODE_F zeroed
#pragma unroll
  for (int p = 0; p < 8; ++p) {
    int idx = tid + p * 256;
    int r = idx >> 5, c = idx & 31;
    int n = min(n0 + r, NN - 1);
    As[r * AP + c] = (c < NODE_F) ? x[(size_t)n * NODE_F + c] : 0.f;
  }
  float acc[4][8];
  init_bias(acc, b0, tx);
  __syncthreads();
  load_B(Bs, W0, NODE_F, 0, tid);
  __syncthreads();
  fma32(As, Bs, acc, ty, tx, 0);

  __syncthreads(); store_relu(As, acc, ty, tx);
  layer_As(As, Bs, W1, b1, L, acc, tid, ty, tx);
  __syncthreads(); store_relu(As, acc, ty, tx);
  layer_As(As, Bs, W2, b2, L, acc, tid, ty, tx);
  lnorm(acc, g, bt, tx);
#pragma unroll
  for (int i = 0; i < 4; ++i) {
    int n = n0 + ty + 16 * i;
    if (n < NN)
#pragma unroll
      for (int j = 0; j < 8; ++j) hx[(size_t)n * L + tx + 16 * j] = acc[i][j];
  }
}

__global__ __launch_bounds__(256) void enc_edge_kernel(
    const float* __restrict__ ea,
    const float* __restrict__ W0, const float* __restrict__ b0,
    const float* __restrict__ W1, const float* __restrict__ b1,
    const float* __restrict__ W2, const float* __restrict__ b2,
    const float* __restrict__ g, const float* __restrict__ bt,
    float* __restrict__ he) {
  __shared__ float As[64 * AP];
  __shared__ float Bs[128 * BP];
  int tid = threadIdx.x, ty = tid >> 4, tx = tid & 15;
  int e0 = blockIdx.x * 64;
#pragma unroll
  for (int p = 0; p < 8; ++p) {
    int idx = tid + p * 256;
    int r = idx >> 5, c = idx & 31;
    int e = min(e0 + r, NE - 1);
    As[r * AP + c] = (c < EDGE_F) ? ea[(size_t)e * EDGE_F + c] : 0.f;
  }
  float acc[4][8];
  init_bias(acc, b0, tx);
  __syncthreads();
  load_B(Bs, W0, EDGE_F, 0, tid);
  __syncthreads();
  fma32(As, Bs, acc, ty, tx, 0);

  __syncthreads(); store_relu(As, acc, ty, tx);
  layer_As(As, Bs, W1, b1, L, acc, tid, ty, tx);
  __syncthreads(); store_relu(As, acc, ty, tx);
  layer_As(As, Bs, W2, b2, L, acc, tid, ty, tx);
  lnorm(acc, g, bt, tx);
#pragma unroll
  for (int i = 0; i < 4; ++i) {
    int e = e0 + ty + 16 * i;
    if (e < NE)
#pragma unroll
      for (int j = 0; j < 8; ++j) he[(size_t)e * L + tx + 16 * j] = acc[i][j];
  }
}

__global__ __launch_bounds__(256) void edge_step_kernel(
    const float* __restrict__ hx, float* __restrict__ he, float* __restrict__ agg,
    const int* __restrict__ ei,
    const float* __restrict__ W0, const float* __restrict__ b0,
    const float* __restrict__ W1, const float* __restrict__ b1,
    const float* __restrict__ W2, const float* __restrict__ b2,
    const float* __restrict__ g, const float* __restrict__ bt) {
  __shared__ float As[64 * AP];
  __shared__ float Bs[128 * BP];
  __shared__ int sidx[64], didx[64], eidx[64];
  int tid = threadIdx.x, ty = tid >> 4, tx = tid & 15;
  int e0 = blockIdx.x * 64;
  if (tid < 64) {
    int e = e0 + tid;
    int ec = e < NE ? e : NE - 1;
    sidx[tid] = ei[ec];        // src
    didx[tid] = ei[NE + ec];   // dst
    eidx[tid] = ec;
  }
  float acc[4][8];
  init_bias(acc, b0, tx);
  // layer0: K=384 = [hx[src] | hx[dst] | he]
  for (int ac = 0; ac < 3; ++ac) {
    __syncthreads();           // idx tables ready / prior As+Bs use done
    if (ac == 0)      fillA_gather(As, hx, sidx, tid);
    else if (ac == 1) fillA_gather(As, hx, didx, tid);
    else              fillA_gather(As, he, eidx, tid);
    for (int bc = 0; bc < 4; ++bc) {
      __syncthreads();
      load_B(Bs, W0, 384, ac * 128 + bc * 32, tid);
      __syncthreads();
      fma32(As, Bs, acc, ty, tx, bc * 32);
    }
  }
  __syncthreads(); store_relu(As, acc, ty, tx);
  layer_As(As, Bs, W1, b1, L, acc, tid, ty, tx);
  __syncthreads(); store_relu(As, acc, ty, tx);
  layer_As(As, Bs, W2, b2, L, acc, tid, ty, tx);
  lnorm(acc, g, bt, tx);
  // epilogue: he += ue ; agg[dst] += ue (device-scope atomics)
#pragma unroll
  for (int i = 0; i < 4; ++i) {
    int r = ty + 16 * i;
    int e = e0 + r;
    if (e < NE) {
      int d = didx[r];
#pragma unroll
      for (int j = 0; j < 8; ++j) {
        int c = tx + 16 * j;
        float ue = acc[i][j];
        he[(size_t)e * L + c] += ue;
        atomicAdd(&agg[(size_t)d * L + c], ue);
      }
    }
  }
}

__global__ __launch_bounds__(256) void node_step_kernel(
    float* __restrict__ hx, const float* __restrict__ agg,
    const float* __restrict__ W0, const float* __restrict__ b0,
    const float* __restrict__ W1, const float* __restrict__ b1,
    const float* __restrict__ W2, const float* __restrict__ b2,
    const float* __restrict__ g, const float* __restrict__ bt) {
  __shared__ float As[64 * AP];
  __shared__ float Bs[128 * BP];
  __shared__ int nidx[64];
  int tid = threadIdx.x, ty = tid >> 4, tx = tid & 15;
  int n0 = blockIdx.x * 64;
  if (tid < 64) nidx[tid] = min(n0 + tid, NN - 1);
  float acc[4][8];
  init_bias(acc, b0, tx);
  // layer0: K=256 = [hx | agg]
  for (int ac = 0; ac < 2; ++ac) {
    __syncthreads();
    fillA_gather(As, ac == 0 ? hx : agg, nidx, tid);
    for (int bc = 0; bc < 4; ++bc) {
      __syncthreads();
      load_B(Bs, W0, 256, ac * 128 + bc * 32, tid);
      __syncthreads();
      fma32(As, Bs, acc, ty, tx, bc * 32);
    }
  }
  __syncthreads(); store_relu(As, acc, ty, tx);
  layer_As(As, Bs, W1, b1, L, acc, tid, ty, tx);
  __syncthreads(); store_relu(As, acc, ty, tx);
  layer_As(As, Bs, W2, b2, L, acc, tid, ty, tx);
  lnorm(acc, g, bt, tx);
#pragma unroll
  for (int i = 0; i < 4; ++i) {
    int n = n0 + ty + 16 * i;
    if (n < NN)
#pragma unroll
      for (int j = 0; j < 8; ++j) hx[(size_t)n * L + tx + 16 * j] += acc[i][j];
  }
}

__global__ __launch_bounds__(256) void dec_kernel(
    const float* __restrict__ hx,
    const float* __restrict__ W0, const float* __restrict__ b0,
    const float* __restrict__ W1, const float* __restrict__ b1,
    const float* __restrict__ W2, const float* __restrict__ b2,
    float* __restrict__ out) {
  __shared__ float As[64 * AP];
  __shared__ float Bs[128 * BP];
  __shared__ int nidx[64];
  int tid = threadIdx.x, ty = tid >> 4, tx = tid & 15;
  int n0 = blockIdx.x * 64;
  if (tid < 64) nidx[tid] = min(n0 + tid, NN - 1);
  __syncthreads();
  fillA_gather(As, hx, nidx, tid);
  float acc[4][8];
  layer_As(As, Bs, W0, b0, L, acc, tid, ty, tx);
  __syncthreads(); store_relu(As, acc, ty, tx);
  layer_As(As, Bs, W1, b1, L, acc, tid, ty, tx);
  __syncthreads(); store_relu(As, acc, ty, tx);
  __syncthreads();
  // final 128 -> 3
  if (tid < 192) {
    int r = tid / 3, o = tid - (tid / 3) * 3;
    int n = n0 + r;
    if (n < NN) {
      float s = b2[o];
#pragma unroll 8
      for (int k = 0; k < L; ++k) s = fmaf(As[r * AP + k], W2[k * 3 + o], s);
      out[(size_t)n * 3 + o] = s;
    }
  }
}

// ---------------- launch ----------------

extern "C" void kernel_launch(void* const* d_in, const int* in_sizes, int n_in,
                              void* d_out, int out_size, void* d_ws, size_t ws_size,
                              hipStream_t stream) {
  (void)in_sizes; (void)n_in; (void)out_size; (void)ws_size;
  const float* x    = (const float*)d_in[0];
  const float* ea   = (const float*)d_in[1];
  const int*   ei   = (const int*)d_in[2];
  const float* enW0 = (const float*)d_in[3];  const float* enb0 = (const float*)d_in[4];
  const float* enW1 = (const float*)d_in[5];  const float* enb1 = (const float*)d_in[6];
  const float* enW2 = (const float*)d_in[7];  const float* enb2 = (const float*)d_in[8];
  const float* eng  = (const float*)d_in[9];  const float* enbt = (const float*)d_in[10];
  const float* eeW0 = (const float*)d_in[11]; const float* eeb0 = (const float*)d_in[12];
  const float* eeW1 = (const float*)d_in[13]; const float* eeb1 = (const float*)d_in[14];
  const float* eeW2 = (const float*)d_in[15]; const float* eeb2 = (const float*)d_in[16];
  const float* eeg  = (const float*)d_in[17]; const float* eebt = (const float*)d_in[18];
  const float* peW0 = (const float*)d_in[19]; const float* peb0 = (const float*)d_in[20];
  const float* peW1 = (const float*)d_in[21]; const float* peb1 = (const float*)d_in[22];
  const float* peW2 = (const float*)d_in[23]; const float* peb2 = (const float*)d_in[24];
  const float* peg  = (const float*)d_in[25]; const float* pebt = (const float*)d_in[26];
  const float* pnW0 = (const float*)d_in[27]; const float* pnb0 = (const float*)d_in[28];
  const float* pnW1 = (const float*)d_in[29]; const float* pnb1 = (const float*)d_in[30];
  const float* pnW2 = (const float*)d_in[31]; const float* pnb2 = (const float*)d_in[32];
  const float* png  = (const float*)d_in[33]; const float* pnbt = (const float*)d_in[34];
  const float* dW0  = (const float*)d_in[35]; const float* db0  = (const float*)d_in[36];
  const float* dW1  = (const float*)d_in[37]; const float* db1  = (const float*)d_in[38];
  const float* dW2  = (const float*)d_in[39]; const float* db2  = (const float*)d_in[40];

  float* hx  = (float*)d_ws;                       // NN*L
  float* he  = hx + (size_t)NN * L;                // NE*L
  float* agg = he + (size_t)NE * L;                // NN*L

  dim3 blk(256);
  int grid_n = (NN + 63) / 64;   // 157
  int grid_e = (NE + 63) / 64;   // 1563

  enc_node_kernel<<<grid_n, blk, 0, stream>>>(x, enW0, enb0, enW1, enb1, enW2, enb2, eng, enbt, hx);
  enc_edge_kernel<<<grid_e, blk, 0, stream>>>(ea, eeW0, eeb0, eeW1, eeb1, eeW2, eeb2, eeg, eebt, he);

  for (int s = 0; s < STEPS; ++s) {
    hipMemsetAsync(agg, 0, (size_t)NN * L * sizeof(float), stream);
    edge_step_kernel<<<grid_e, blk, 0, stream>>>(
        hx, he, agg, ei,
        peW0 + (size_t)s * 384 * L, peb0 + (size_t)s * L,
        peW1 + (size_t)s * L * L,   peb1 + (size_t)s * L,
        peW2 + (size_t)s * L * L,   peb2 + (size_t)s * L,
        peg + (size_t)s * L,        pebt + (size_t)s * L);
    node_step_kernel<<<grid_n, blk, 0, stream>>>(
        hx, agg,
        pnW0 + (size_t)s * 256 * L, pnb0 + (size_t)s * L,
        pnW1 + (size_t)s * L * L,   pnb1 + (size_t)s * L,
        pnW2 + (size_t)s * L * L,   pnb2 + (size_t)s * L,
        png + (size_t)s * L,        pnbt + (size_t)s * L);
  }

  dec_kernel<<<grid_n, blk, 0, stream>>>(hx, dW0, db0, dW1, db1, dW2, db2, (float*)d_out);
}

// Round 2
// 1398.883 us; speedup vs baseline: 5.0499x; 5.0499x over previous
//
#include <hip/hip_runtime.h>

// EncodeProcessDecode (GNS): N=10000 nodes, E=100000 edges, S=10 steps, L=H=128.
// Round 2: bf16 MFMA (16x16x32) for edge/node processor steps + edge encoder.
// Activations/residuals stay fp32; weights pre-transposed to bf16 [n][k] in ws.

#define NN 10000
#define NE 100000
#define STEPS 10
#define NODE_F 30
#define EDGE_F 4
#define L 128
#define AP 132   // fp32 helper LDS stride (old kernels)
#define BP 36

#define WS_STRIDE 136   // bf16 elems per LDS row: 128 + 8 pad (272B = 17*16B)
#define AB_STRIDE 136

typedef __bf16 bf16x8 __attribute__((ext_vector_type(8)));
typedef float f32x4 __attribute__((ext_vector_type(4)));

// ================= MFMA-path helpers =================

// Stage one 128k x 128n bf16 weight section into LDS [n][WS_STRIDE].
__device__ __forceinline__ void stage_W(unsigned short* __restrict__ Ws,
                                        const unsigned short* __restrict__ Wt,
                                        int K, int sec, int tid) {
#pragma unroll
  for (int p = 0; p < 8; ++p) {
    int u = tid + p * 256;
    int n = u >> 4, kk = u & 15;
    uint4 v = *(const uint4*)(Wt + (size_t)n * K + sec * 128 + kk * 8);
    *(uint4*)&Ws[n * WS_STRIDE + kk * 8] = v;
  }
}

__device__ __forceinline__ bf16x8 cvt8(float4 f0, float4 f1) {
  bf16x8 r;
  r[0] = (__bf16)f0.x; r[1] = (__bf16)f0.y; r[2] = (__bf16)f0.z; r[3] = (__bf16)f0.w;
  r[4] = (__bf16)f1.x; r[5] = (__bf16)f1.y; r[6] = (__bf16)f1.z; r[7] = (__bf16)f1.w;
  return r;
}

__device__ __forceinline__ void init_acc(f32x4 acc[2][4], const float* __restrict__ b,
                                         int wcol, int l16) {
#pragma unroll
  for (int j = 0; j < 4; ++j) {
    float bv = b[wcol + j * 16 + l16];
#pragma unroll
    for (int i = 0; i < 2; ++i) acc[i][j] = f32x4{bv, bv, bv, bv};
  }
}

// 4 chunks (K=128), A from global fp32 rows (2 row-pointers), B from LDS.
__device__ __forceinline__ void layer_glb(const float* __restrict__ ap0,
                                          const float* __restrict__ ap1,
                                          const unsigned short* __restrict__ Ws,
                                          f32x4 acc[2][4], int wcol, int l4, int l16) {
#pragma unroll
  for (int kk = 0; kk < 4; ++kk) {
    bf16x8 af[2];
    const float* p0 = ap0 + kk * 32 + l4 * 8;
    af[0] = cvt8(*(const float4*)p0, *(const float4*)(p0 + 4));
    const float* p1 = ap1 + kk * 32 + l4 * 8;
    af[1] = cvt8(*(const float4*)p1, *(const float4*)(p1 + 4));
#pragma unroll
    for (int j = 0; j < 4; ++j) {
      bf16x8 bv = *(const bf16x8*)&Ws[(wcol + j * 16 + l16) * WS_STRIDE + kk * 32 + l4 * 8];
#pragma unroll
      for (int i = 0; i < 2; ++i)
        acc[i][j] = __builtin_amdgcn_mfma_f32_16x16x32_bf16(af[i], bv, acc[i][j], 0, 0, 0);
    }
  }
}

// 4 chunks (K=128), A from LDS bf16 (Ab), B from LDS.
__device__ __forceinline__ void layer_lds(const unsigned short* __restrict__ Ab,
                                          const unsigned short* __restrict__ Ws,
                                          f32x4 acc[2][4], int wrow, int wcol, int l4, int l16) {
#pragma unroll
  for (int kk = 0; kk < 4; ++kk) {
    bf16x8 af[2];
#pragma unroll
    for (int i = 0; i < 2; ++i)
      af[i] = *(const bf16x8*)&Ab[(wrow + i * 16 + l16) * AB_STRIDE + kk * 32 + l4 * 8];
#pragma unroll
    for (int j = 0; j < 4; ++j) {
      bf16x8 bv = *(const bf16x8*)&Ws[(wcol + j * 16 + l16) * WS_STRIDE + kk * 32 + l4 * 8];
#pragma unroll
      for (int i = 0; i < 2; ++i)
        acc[i][j] = __builtin_amdgcn_mfma_f32_16x16x32_bf16(af[i], bv, acc[i][j], 0, 0, 0);
    }
  }
}

__device__ __forceinline__ void relu_to_Ab(unsigned short* __restrict__ Ab, f32x4 acc[2][4],
                                           int wrow, int wcol, int l4, int l16) {
#pragma unroll
  for (int i = 0; i < 2; ++i)
#pragma unroll
    for (int j = 0; j < 4; ++j)
#pragma unroll
      for (int r = 0; r < 4; ++r) {
        int row = wrow + i * 16 + l4 * 4 + r;
        int col = wcol + j * 16 + l16;
        __bf16 v = (__bf16)fmaxf(acc[i][j][r], 0.f);
        Ab[row * AB_STRIDE + col] = __builtin_bit_cast(unsigned short, v);
      }
}

// LayerNorm stats: per-(i,r) partial sums over this wave's 64 cols, 16-lane reduce,
// cross-half combine via red[] (overlaid on Ab). Call pattern:
//   compute ps/ps2 -> sync -> write red -> sync -> read red.
__device__ __forceinline__ void ln_partials(const f32x4 acc[2][4], float ps[2][4], float ps2[2][4]) {
#pragma unroll
  for (int i = 0; i < 2; ++i)
#pragma unroll
    for (int r = 0; r < 4; ++r) {
      float s = 0.f, s2 = 0.f;
#pragma unroll
      for (int j = 0; j < 4; ++j) { float v = acc[i][j][r]; s += v; s2 += v * v; }
#pragma unroll
      for (int off = 1; off < 16; off <<= 1) {
        s += __shfl_xor(s, off, 64);
        s2 += __shfl_xor(s2, off, 64);
      }
      ps[i][r] = s; ps2[i][r] = s2;
    }
}

// ================= MFMA kernels =================

__global__ __launch_bounds__(256) void edge_step_mfma(
    const float* __restrict__ hx, float* __restrict__ he, float* __restrict__ agg,
    const int* __restrict__ ei,
    const unsigned short* __restrict__ W0t, const float* __restrict__ b0,
    const unsigned short* __restrict__ W1t, const float* __restrict__ b1,
    const unsigned short* __restrict__ W2t, const float* __restrict__ b2,
    const float* __restrict__ g, const float* __restrict__ bt) {
  __shared__ __align__(16) unsigned short Ws[128 * WS_STRIDE];
  __shared__ __align__(16) unsigned short Ab[64 * AB_STRIDE];
  __shared__ int sidx[64], didx[64];
  int tid = threadIdx.x;
  int w = tid >> 6, lane = tid & 63;
  int l4 = lane >> 4, l16 = lane & 15;
  int wrow = (w >> 1) * 32, wcol = (w & 1) * 64;
  int e0 = blockIdx.x * 64;
  if (tid < 64) {
    int e = min(e0 + tid, NE - 1);
    sidx[tid] = ei[e];
    didx[tid] = ei[NE + e];
  }
  f32x4 acc[2][4];
  init_acc(acc, b0, wcol, l16);
  __syncthreads();
  // ---- layer0: K=384 = [hx[src] | hx[dst] | he] ----
  for (int sec = 0; sec < 3; ++sec) {
    stage_W(Ws, W0t, 384, sec, tid);
    const float* ap[2];
#pragma unroll
    for (int i = 0; i < 2; ++i) {
      int r = wrow + i * 16 + l16;
      if (sec == 0)      ap[i] = hx + (size_t)sidx[r] * L;
      else if (sec == 1) ap[i] = hx + (size_t)didx[r] * L;
      else               ap[i] = he + (size_t)min(e0 + r, NE - 1) * L;
    }
    __syncthreads();
    layer_glb(ap[0], ap[1], Ws, acc, wcol, l4, l16);
    __syncthreads();
  }
  // ---- layer1 ----
  relu_to_Ab(Ab, acc, wrow, wcol, l4, l16);
  stage_W(Ws, W1t, 128, 0, tid);
  init_acc(acc, b1, wcol, l16);
  __syncthreads();
  layer_lds(Ab, Ws, acc, wrow, wcol, l4, l16);
  __syncthreads();
  // ---- layer2 (no relu after) ----
  relu_to_Ab(Ab, acc, wrow, wcol, l4, l16);
  stage_W(Ws, W2t, 128, 0, tid);
  init_acc(acc, b2, wcol, l16);
  __syncthreads();
  layer_lds(Ab, Ws, acc, wrow, wcol, l4, l16);
  // ---- LayerNorm ----
  float ps[2][4], ps2[2][4];
  ln_partials(acc, ps, ps2);
  __syncthreads();                       // Ab reads done; red overlays Ab
  float* red = (float*)Ab;               // [2 halves][64 rows][2]
  if (l16 == 0) {
#pragma unroll
    for (int i = 0; i < 2; ++i)
#pragma unroll
      for (int r = 0; r < 4; ++r) {
        int row = wrow + i * 16 + l4 * 4 + r;
        red[(w & 1) * 128 + row * 2 + 0] = ps[i][r];
        red[(w & 1) * 128 + row * 2 + 1] = ps2[i][r];
      }
  }
  __syncthreads();
  float gv[4], btv[4];
#pragma unroll
  for (int j = 0; j < 4; ++j) {
    int col = wcol + j * 16 + l16;
    gv[j] = g[col]; btv[j] = bt[col];
  }
#pragma unroll
  for (int i = 0; i < 2; ++i)
#pragma unroll
    for (int r = 0; r < 4; ++r) {
      int row = wrow + i * 16 + l4 * 4 + r;
      float s  = red[row * 2]     + red[128 + row * 2];
      float s2 = red[row * 2 + 1] + red[128 + row * 2 + 1];
      float m = s * (1.f / 128.f);
      float inv = rsqrtf(s2 * (1.f / 128.f) - m * m + 1e-5f);
      int e = e0 + row;
      if (e < NE) {
        int d = didx[row];
        size_t hoff = (size_t)e * L;
#pragma unroll
        for (int j = 0; j < 4; ++j) {
          int col = wcol + j * 16 + l16;
          float ue = (acc[i][j][r] - m) * inv * gv[j] + btv[j];
          he[hoff + col] += ue;
          atomicAdd(&agg[(size_t)d * L + col], ue);
        }
      }
    }
}

__global__ __launch_bounds__(256) void node_step_mfma(
    float* __restrict__ hx, const float* __restrict__ agg,
    const unsigned short* __restrict__ W0t, const float* __restrict__ b0,
    const unsigned short* __restrict__ W1t, const float* __restrict__ b1,
    const unsigned short* __restrict__ W2t, const float* __restrict__ b2,
    const float* __restrict__ g, const float* __restrict__ bt) {
  __shared__ __align__(16) unsigned short Ws[128 * WS_STRIDE];
  __shared__ __align__(16) unsigned short Ab[64 * AB_STRIDE];
  int tid = threadIdx.x;
  int w = tid >> 6, lane = tid & 63;
  int l4 = lane >> 4, l16 = lane & 15;
  int wrow = (w >> 1) * 32, wcol = (w & 1) * 64;
  int n0 = blockIdx.x * 64;
  f32x4 acc[2][4];
  init_acc(acc, b0, wcol, l16);
  // ---- layer0: K=256 = [hx | agg] ----
  for (int sec = 0; sec < 2; ++sec) {
    __syncthreads();
    stage_W(Ws, W0t, 256, sec, tid);
    const float* base = (sec == 0) ? hx : agg;
    const float* ap[2];
#pragma unroll
    for (int i = 0; i < 2; ++i)
      ap[i] = base + (size_t)min(n0 + wrow + i * 16 + l16, NN - 1) * L;
    __syncthreads();
    layer_glb(ap[0], ap[1], Ws, acc, wcol, l4, l16);
  }
  __syncthreads();
  // ---- layer1 ----
  relu_to_Ab(Ab, acc, wrow, wcol, l4, l16);
  stage_W(Ws, W1t, 128, 0, tid);
  init_acc(acc, b1, wcol, l16);
  __syncthreads();
  layer_lds(Ab, Ws, acc, wrow, wcol, l4, l16);
  __syncthreads();
  // ---- layer2 ----
  relu_to_Ab(Ab, acc, wrow, wcol, l4, l16);
  stage_W(Ws, W2t, 128, 0, tid);
  init_acc(acc, b2, wcol, l16);
  __syncthreads();
  layer_lds(Ab, Ws, acc, wrow, wcol, l4, l16);
  // ---- LayerNorm + residual ----
  float ps[2][4], ps2[2][4];
  ln_partials(acc, ps, ps2);
  __syncthreads();
  float* red = (float*)Ab;
  if (l16 == 0) {
#pragma unroll
    for (int i = 0; i < 2; ++i)
#pragma unroll
      for (int r = 0; r < 4; ++r) {
        int row = wrow + i * 16 + l4 * 4 + r;
        red[(w & 1) * 128 + row * 2 + 0] = ps[i][r];
        red[(w & 1) * 128 + row * 2 + 1] = ps2[i][r];
      }
  }
  __syncthreads();
  float gv[4], btv[4];
#pragma unroll
  for (int j = 0; j < 4; ++j) {
    int col = wcol + j * 16 + l16;
    gv[j] = g[col]; btv[j] = bt[col];
  }
#pragma unroll
  for (int i = 0; i < 2; ++i)
#pragma unroll
    for (int r = 0; r < 4; ++r) {
      int row = wrow + i * 16 + l4 * 4 + r;
      float s  = red[row * 2]     + red[128 + row * 2];
      float s2 = red[row * 2 + 1] + red[128 + row * 2 + 1];
      float m = s * (1.f / 128.f);
      float inv = rsqrtf(s2 * (1.f / 128.f) - m * m + 1e-5f);
      int n = n0 + row;
      if (n < NN) {
#pragma unroll
        for (int j = 0; j < 4; ++j) {
          int col = wcol + j * 16 + l16;
          float un = (acc[i][j][r] - m) * inv * gv[j] + btv[j];
          hx[(size_t)n * L + col] += un;
        }
      }
    }
}

__global__ __launch_bounds__(256) void enc_edge_mfma(
    const float* __restrict__ ea,
    const float* __restrict__ W0, const float* __restrict__ b0,
    const unsigned short* __restrict__ W1t, const float* __restrict__ b1,
    const unsigned short* __restrict__ W2t, const float* __restrict__ b2,
    const float* __restrict__ g, const float* __restrict__ bt,
    float* __restrict__ he) {
  __shared__ __align__(16) unsigned short Ws[128 * WS_STRIDE];
  __shared__ __align__(16) unsigned short Ab[64 * AB_STRIDE];
  int tid = threadIdx.x;
  int w = tid >> 6, lane = tid & 63;
  int l4 = lane >> 4, l16 = lane & 15;
  int wrow = (w >> 1) * 32, wcol = (w & 1) * 64;
  int e0 = blockIdx.x * 64;
  // ---- layer0 (K=4) computed directly in fp32, written bf16 to Ab ----
  {
    int row = tid >> 2, cbase = (tid & 3) * 32;
    int e = min(e0 + row, NE - 1);
    float4 eav = *(const float4*)&ea[(size_t)e * 4];
#pragma unroll
    for (int c = 0; c < 32; ++c) {
      int col = cbase + c;
      float sum = b0[col] + eav.x * W0[col] + eav.y * W0[128 + col] +
                  eav.z * W0[256 + col] + eav.w * W0[384 + col];
      __bf16 v = (__bf16)fmaxf(sum, 0.f);
      Ab[row * AB_STRIDE + col] = __builtin_bit_cast(unsigned short, v);
    }
  }
  stage_W(Ws, W1t, 128, 0, tid);
  f32x4 acc[2][4];
  init_acc(acc, b1, wcol, l16);
  __syncthreads();
  layer_lds(Ab, Ws, acc, wrow, wcol, l4, l16);
  __syncthreads();
  relu_to_Ab(Ab, acc, wrow, wcol, l4, l16);
  stage_W(Ws, W2t, 128, 0, tid);
  init_acc(acc, b2, wcol, l16);
  __syncthreads();
  layer_lds(Ab, Ws, acc, wrow, wcol, l4, l16);
  // ---- LayerNorm ----
  float ps[2][4], ps2[2][4];
  ln_partials(acc, ps, ps2);
  __syncthreads();
  float* red = (float*)Ab;
  if (l16 == 0) {
#pragma unroll
    for (int i = 0; i < 2; ++i)
#pragma unroll
      for (int r = 0; r < 4; ++r) {
        int row = wrow + i * 16 + l4 * 4 + r;
        red[(w & 1) * 128 + row * 2 + 0] = ps[i][r];
        red[(w & 1) * 128 + row * 2 + 1] = ps2[i][r];
      }
  }
  __syncthreads();
  float gv[4], btv[4];
#pragma unroll
  for (int j = 0; j < 4; ++j) {
    int col = wcol + j * 16 + l16;
    gv[j] = g[col]; btv[j] = bt[col];
  }
#pragma unroll
  for (int i = 0; i < 2; ++i)
#pragma unroll
    for (int r = 0; r < 4; ++r) {
      int row = wrow + i * 16 + l4 * 4 + r;
      float s  = red[row * 2]     + red[128 + row * 2];
      float s2 = red[row * 2 + 1] + red[128 + row * 2 + 1];
      float m = s * (1.f / 128.f);
      float inv = rsqrtf(s2 * (1.f / 128.f) - m * m + 1e-5f);
      int e = e0 + row;
      if (e < NE) {
#pragma unroll
        for (int j = 0; j < 4; ++j) {
          int col = wcol + j * 16 + l16;
          he[(size_t)e * L + col] = (acc[i][j][r] - m) * inv * gv[j] + btv[j];
        }
      }
    }
}

// ================= weight prep =================

// Transpose fp32 [K][128] -> bf16 [128][K] for a stacked (S-step) MLP triple.
// out per step: [W0t(128*K0)][W1t(128*128)][W2t(128*128)]
__global__ __launch_bounds__(256) void wprep_kernel(
    const float* __restrict__ W0, const float* __restrict__ W1, const float* __restrict__ W2,
    unsigned short* __restrict__ out, int K0, int steps) {
  int per_step = 128 * (K0 + 256);
  int idx = blockIdx.x * 256 + threadIdx.x;
  if (idx >= steps * per_step) return;
  int s = idx / per_step, r = idx - s * per_step;
  float v;
  if (r < 128 * K0) {
    int n = r / K0, k = r - n * K0;
    v = W0[(size_t)s * K0 * 128 + (size_t)k * 128 + n];
  } else {
    r -= 128 * K0;
    const float* W = (r < 16384) ? W1 : W2;
    r &= 16383;
    int n = r >> 7, k = r & 127;
    v = W[(size_t)s * 16384 + k * 128 + n];
  }
  __bf16 b = (__bf16)v;
  out[idx] = __builtin_bit_cast(unsigned short, b);
}

// Transpose two single 128x128 fp32 matrices -> bf16 [128][128] (edge encoder W1,W2).
__global__ __launch_bounds__(256) void tprep_kernel(
    const float* __restrict__ W1, const float* __restrict__ W2, unsigned short* __restrict__ out) {
  int idx = blockIdx.x * 256 + threadIdx.x;   // < 32768
  const float* W = (idx < 16384) ? W1 : W2;
  int r = idx & 16383;
  int n = r >> 7, k = r & 127;
  __bf16 b = (__bf16)W[k * 128 + n];
  out[idx] = __builtin_bit_cast(unsigned short, b);
}

// ================= fp32 helpers (encoder-node / decoder, unchanged) =================

__device__ __forceinline__ void load_B(float* __restrict__ Bs, const float* __restrict__ W,
                                       int K, int k0, int tid) {
#pragma unroll
  for (int p = 0; p < 16; ++p) {
    int idx = tid + p * 256;
    int kk = idx >> 7;
    int c = idx & 127;
    float v = 0.f;
    if (k0 + kk < K) v = W[(size_t)(k0 + kk) * L + c];
    Bs[c * BP + kk] = v;
  }
}

__device__ __forceinline__ void fma32(const float* __restrict__ As, const float* __restrict__ Bs,
                                      float acc[4][8], int ty, int tx, int koff) {
#pragma unroll
  for (int kk = 0; kk < 32; kk += 4) {
    float4 a[4];
    float4 b[8];
#pragma unroll
    for (int i = 0; i < 4; ++i)
      a[i] = *(const float4*)&As[(ty + 16 * i) * AP + koff + kk];
#pragma unroll
    for (int j = 0; j < 8; ++j)
      b[j] = *(const float4*)&Bs[(tx + 16 * j) * BP + kk];
#pragma unroll
    for (int i = 0; i < 4; ++i)
#pragma unroll
      for (int j = 0; j < 8; ++j) {
        acc[i][j] = fmaf(a[i].x, b[j].x, acc[i][j]);
        acc[i][j] = fmaf(a[i].y, b[j].y, acc[i][j]);
        acc[i][j] = fmaf(a[i].z, b[j].z, acc[i][j]);
        acc[i][j] = fmaf(a[i].w, b[j].w, acc[i][j]);
      }
  }
}

__device__ __forceinline__ void init_bias(float acc[4][8], const float* __restrict__ b, int tx) {
#pragma unroll
  for (int j = 0; j < 8; ++j) {
    float bv = b[tx + 16 * j];
#pragma unroll
    for (int i = 0; i < 4; ++i) acc[i][j] = bv;
  }
}

__device__ __forceinline__ void store_relu(float* __restrict__ As, float acc[4][8], int ty, int tx) {
#pragma unroll
  for (int i = 0; i < 4; ++i)
#pragma unroll
    for (int j = 0; j < 8; ++j)
      As[(ty + 16 * i) * AP + tx + 16 * j] = fmaxf(acc[i][j], 0.f);
}

__device__ __forceinline__ void layer_As(const float* __restrict__ As, float* __restrict__ Bs,
                                         const float* __restrict__ W, const float* __restrict__ bias,
                                         int K, float acc[4][8], int tid, int ty, int tx) {
  init_bias(acc, bias, tx);
  int nc = (K + 31) >> 5;
  for (int bc = 0; bc < nc; ++bc) {
    __syncthreads();
    load_B(Bs, W, K, bc * 32, tid);
    __syncthreads();
    fma32(As, Bs, acc, ty, tx, bc * 32);
  }
}

__device__ __forceinline__ void fillA_gather(float* __restrict__ As, const float* __restrict__ base,
                                             const int* __restrict__ ridx, int tid) {
#pragma unroll
  for (int p = 0; p < 8; ++p) {
    int idx = tid + p * 256;
    int r = idx >> 5;
    int c4 = idx & 31;
    float4 v = *(const float4*)&base[(size_t)ridx[r] * L + c4 * 4];
    *(float4*)&As[r * AP + c4 * 4] = v;
  }
}

__device__ __forceinline__ void lnorm(float acc[4][8], const float* __restrict__ g,
                                      const float* __restrict__ bt, int tx) {
  float gv[8], bv[8];
#pragma unroll
  for (int j = 0; j < 8; ++j) { gv[j] = g[tx + 16 * j]; bv[j] = bt[tx + 16 * j]; }
#pragma unroll
  for (int i = 0; i < 4; ++i) {
    float s = 0.f, s2 = 0.f;
#pragma unroll
    for (int j = 0; j < 8; ++j) { s += acc[i][j]; s2 += acc[i][j] * acc[i][j]; }
#pragma unroll
    for (int off = 1; off < 16; off <<= 1) {
      s  += __shfl_xor(s, off, 64);
      s2 += __shfl_xor(s2, off, 64);
    }
    float m = s * (1.f / 128.f);
    float var = s2 * (1.f / 128.f) - m * m;
    float inv = rsqrtf(var + 1e-5f);
#pragma unroll
    for (int j = 0; j < 8; ++j) acc[i][j] = (acc[i][j] - m) * inv * gv[j] + bv[j];
  }
}

__global__ __launch_bounds__(256) void enc_node_kernel(
    const float* __restrict__ x,
    const float* __restrict__ W0, const float* __restrict__ b0,
    const float* __restrict__ W1, const float* __restrict__ b1,
    const float* __restrict__ W2, const float* __restrict__ b2,
    const float* __restrict__ g, const float* __restrict__ bt,
    float* __restrict__ hx) {
  __shared__ float As[64 * AP];
  __shared__ float Bs[128 * BP];
  int tid = threadIdx.x, ty = tid >> 4, tx = tid & 15;
  int n0 = blockIdx.x * 64;
#pragma unroll
  for (int p = 0; p < 8; ++p) {
    int idx = tid + p * 256;
    int r = idx >> 5, c = idx & 31;
    int n = min(n0 + r, NN - 1);
    As[r * AP + c] = (c < NODE_F) ? x[(size_t)n * NODE_F + c] : 0.f;
  }
  float acc[4][8];
  init_bias(acc, b0, tx);
  __syncthreads();
  load_B(Bs, W0, NODE_F, 0, tid);
  __syncthreads();
  fma32(As, Bs, acc, ty, tx, 0);

  __syncthreads(); store_relu(As, acc, ty, tx);
  layer_As(As, Bs, W1, b1, L, acc, tid, ty, tx);
  __syncthreads(); store_relu(As, acc, ty, tx);
  layer_As(As, Bs, W2, b2, L, acc, tid, ty, tx);
  lnorm(acc, g, bt, tx);
#pragma unroll
  for (int i = 0; i < 4; ++i) {
    int n = n0 + ty + 16 * i;
    if (n < NN)
#pragma unroll
      for (int j = 0; j < 8; ++j) hx[(size_t)n * L + tx + 16 * j] = acc[i][j];
  }
}

__global__ __launch_bounds__(256) void dec_kernel(
    const float* __restrict__ hx,
    const float* __restrict__ W0, const float* __restrict__ b0,
    const float* __restrict__ W1, const float* __restrict__ b1,
    const float* __restrict__ W2, const float* __restrict__ b2,
    float* __restrict__ out) {
  __shared__ float As[64 * AP];
  __shared__ float Bs[128 * BP];
  __shared__ int nidx[64];
  int tid = threadIdx.x, ty = tid >> 4, tx = tid & 15;
  int n0 = blockIdx.x * 64;
  if (tid < 64) nidx[tid] = min(n0 + tid, NN - 1);
  __syncthreads();
  fillA_gather(As, hx, nidx, tid);
  float acc[4][8];
  layer_As(As, Bs, W0, b0, L, acc, tid, ty, tx);
  __syncthreads(); store_relu(As, acc, ty, tx);
  layer_As(As, Bs, W1, b1, L, acc, tid, ty, tx);
  __syncthreads(); store_relu(As, acc, ty, tx);
  __syncthreads();
  if (tid < 192) {
    int r = tid / 3, o = tid - (tid / 3) * 3;
    int n = n0 + r;
    if (n < NN) {
      float s = b2[o];
#pragma unroll 8
      for (int k = 0; k < L; ++k) s = fmaf(As[r * AP + k], W2[k * 3 + o], s);
      out[(size_t)n * 3 + o] = s;
    }
  }
}

// ================= launch =================

extern "C" void kernel_launch(void* const* d_in, const int* in_sizes, int n_in,
                              void* d_out, int out_size, void* d_ws, size_t ws_size,
                              hipStream_t stream) {
  (void)in_sizes; (void)n_in; (void)out_size; (void)ws_size;
  const float* x    = (const float*)d_in[0];
  const float* ea   = (const float*)d_in[1];
  const int*   ei   = (const int*)d_in[2];
  const float* enW0 = (const float*)d_in[3];  const float* enb0 = (const float*)d_in[4];
  const float* enW1 = (const float*)d_in[5];  const float* enb1 = (const float*)d_in[6];
  const float* enW2 = (const float*)d_in[7];  const float* enb2 = (const float*)d_in[8];
  const float* eng  = (const float*)d_in[9];  const float* enbt = (const float*)d_in[10];
  const float* eeW0 = (const float*)d_in[11]; const float* eeb0 = (const float*)d_in[12];
  const float* eeW1 = (const float*)d_in[13]; const float* eeb1 = (const float*)d_in[14];
  const float* eeW2 = (const float*)d_in[15]; const float* eeb2 = (const float*)d_in[16];
  const float* eeg  = (const float*)d_in[17]; const float* eebt = (const float*)d_in[18];
  const float* peW0 = (const float*)d_in[19]; const float* peb0 = (const float*)d_in[20];
  const float* peW1 = (const float*)d_in[21]; const float* peb1 = (const float*)d_in[22];
  const float* peW2 = (const float*)d_in[23]; const float* peb2 = (const float*)d_in[24];
  const float* peg  = (const float*)d_in[25]; const float* pebt = (const float*)d_in[26];
  const float* pnW0 = (const float*)d_in[27]; const float* pnb0 = (const float*)d_in[28];
  const float* pnW1 = (const float*)d_in[29]; const float* pnb1 = (const float*)d_in[30];
  const float* pnW2 = (const float*)d_in[31]; const float* pnb2 = (const float*)d_in[32];
  const float* png  = (const float*)d_in[33]; const float* pnbt = (const float*)d_in[34];
  const float* dW0  = (const float*)d_in[35]; const float* db0  = (const float*)d_in[36];
  const float* dW1  = (const float*)d_in[37]; const float* db1  = (const float*)d_in[38];
  const float* dW2  = (const float*)d_in[39]; const float* db2  = (const float*)d_in[40];

  float* hx  = (float*)d_ws;                       // NN*L fp32
  float* he  = hx + (size_t)NN * L;                // NE*L fp32
  float* agg = he + (size_t)NE * L;                // NN*L fp32
  unsigned short* wt_pe = (unsigned short*)(agg + (size_t)NN * L);   // 10*81920 bf16
  unsigned short* wt_pn = wt_pe + 819200;                            // 10*65536 bf16
  unsigned short* wt_ee = wt_pn + 655360;                            // 2*16384 bf16

  dim3 blk(256);
  int grid_n = (NN + 63) / 64;   // 157
  int grid_e = (NE + 63) / 64;   // 1563

  wprep_kernel<<<(10 * 81920 + 255) / 256, blk, 0, stream>>>(peW0, peW1, peW2, wt_pe, 384, 10);
  wprep_kernel<<<(10 * 65536 + 255) / 256, blk, 0, stream>>>(pnW0, pnW1, pnW2, wt_pn, 256, 10);
  tprep_kernel<<<128, blk, 0, stream>>>(eeW1, eeW2, wt_ee);

  enc_node_kernel<<<grid_n, blk, 0, stream>>>(x, enW0, enb0, enW1, enb1, enW2, enb2, eng, enbt, hx);
  enc_edge_mfma<<<grid_e, blk, 0, stream>>>(ea, eeW0, eeb0, wt_ee, eeb1, wt_ee + 16384, eeb2, eeg, eebt, he);

  for (int s = 0; s < STEPS; ++s) {
    hipMemsetAsync(agg, 0, (size_t)NN * L * sizeof(float), stream);
    const unsigned short* pe = wt_pe + (size_t)s * 81920;
    const unsigned short* pn = wt_pn + (size_t)s * 65536;
    edge_step_mfma<<<grid_e, blk, 0, stream>>>(
        hx, he, agg, ei,
        pe,                 peb0 + (size_t)s * L,
        pe + 49152,         peb1 + (size_t)s * L,
        pe + 49152 + 16384, peb2 + (size_t)s * L,
        peg + (size_t)s * L, pebt + (size_t)s * L);
    node_step_mfma<<<grid_n, blk, 0, stream>>>(
        hx, agg,
        pn,                 pnb0 + (size_t)s * L,
        pn + 32768,         pnb1 + (size_t)s * L,
        pn + 32768 + 16384, pnb2 + (size_t)s * L,
        png + (size_t)s * L, pnbt + (size_t)s * L);
  }

  dec_kernel<<<grid_n, blk, 0, stream>>>(hx, dW0, db0, dW1, db1, dW2, db2, (float*)d_out);
}